// Round 8
// baseline (46848.651 us; speedup 1.0000x reference)
//
#include <hip/hip_runtime.h>
#include <cstddef>

#define DEV static __device__ __forceinline__
typedef unsigned long long ull;

DEV float b2f(unsigned short u){ unsigned int i=((unsigned int)u)<<16; float f; __builtin_memcpy(&f,&i,4); return f; }
DEV float lo16(unsigned int u){ unsigned int i=u<<16; float f; __builtin_memcpy(&f,&i,4); return f; }
DEV float hi16(unsigned int u){ unsigned int i=u&0xffff0000u; float f; __builtin_memcpy(&f,&i,4); return f; }
DEV unsigned short f2b(float f){ unsigned int i; __builtin_memcpy(&i,&f,4); unsigned int r=(i+0x7fffu+((i>>16)&1u))>>16; return (unsigned short)r; }
DEV float sigf(float x){ return 1.f/(1.f+__expf(-x)); }
DEV float eluf(float x){ return x>0.f ? x : (__expf(x)-1.f); }
DEV float gload(const void* p, long i, int f32){
  return f32 ? ((const float*)p)[i] : b2f(((const unsigned short*)p)[i]);
}
// tagged-word mailbox: relaxed agent atomics (LLC point, no L2 invalidation)
DEV ull pk(float f, unsigned tag){ unsigned b; __builtin_memcpy(&b,&f,4); return ((ull)tag<<32)|b; }
DEV float upk(ull u){ unsigned b=(unsigned)u; float f; __builtin_memcpy(&f,&b,4); return f; }
DEV void ast64(ull* p, ull v){ __hip_atomic_store(p, v, __ATOMIC_RELAXED, __HIP_MEMORY_SCOPE_AGENT); }
DEV ull ald64(const ull* p){ return __hip_atomic_load(p, __ATOMIC_RELAXED, __HIP_MEMORY_SCOPE_AGENT); }
// poll with backoff: first probe immediate; on miss, sleep ~64 cyc between
// probes. Bounds fabric traffic by construction (r7 post-mortem: unthrottled
// spins at agent scope saturated the fabric -> 30 GB FETCH, 5x regression).
DEV float pollw(const ull* w, unsigned tag){
  ull u = ald64(w);
  while ((unsigned)(u>>32) != tag){ __builtin_amdgcn_s_sleep(1); u = ald64(w); }
  return upk(u);
}

// ---------------------------------------------------------------------------
// Sniff input dtypes. flags[0]=1 if floats are f32; flags[1]=1 if ints are i64.
// ---------------------------------------------------------------------------
__global__ __launch_bounds__(64) void sniff(const void* __restrict__ seqs,
                                            const void* __restrict__ seq_lens,
                                            int* __restrict__ flags)
{
  __shared__ int cnt;
  if (threadIdx.x==0) cnt=0;
  __syncthreads();
  const unsigned short* u = (const unsigned short*)seqs;
  int sane=0;
  for (int i=threadIdx.x;i<1024;i+=64){
    int e = (u[i]>>7)&0xFF;
    if (e>=0x70 && e<=0x8F) sane++;
  }
  atomicAdd(&cnt, sane);
  __syncthreads();
  if (threadIdx.x==0){
    flags[0] = (cnt < 820) ? 1 : 0;
    const int* s = (const int*)seq_lens;
    flags[1] = ((s[1]|s[3]|s[5]|s[7])==0) ? 1 : 0;
  }
}

// ---------------------------------------------------------------------------
// Prep: 4-part-sliced bf16 weights (r6-verified layouts).
// Wl[l][p∈4][k∈512][gi∈256]: g = (gi>>6)*256 + p*64 + (gi&63);
// k<256 -> ih (ctx/h_in) col k, k>=256 -> hh col k-256.
// ---------------------------------------------------------------------------
__global__ __launch_bounds__(256) void prep_transpose(
    const void* __restrict__ Wih0, const void* __restrict__ Whh0,
    const void* __restrict__ Wih1, const void* __restrict__ Whh1,
    const void* __restrict__ Wih2, const void* __restrict__ Whh2,
    const void* __restrict__ kW0,  const void* __restrict__ kW1,
    const void* __restrict__ vW0,  const void* __restrict__ vW1,
    const void* __restrict__ qW0,  const void* __restrict__ qW1,
    const void* __restrict__ bih0, const void* __restrict__ bhh0,
    const void* __restrict__ bih1, const void* __restrict__ bhh1,
    const void* __restrict__ bih2, const void* __restrict__ bhh2,
    const void* __restrict__ outW, const void* __restrict__ inith,
    const void* __restrict__ initc, const void* __restrict__ qb0,
    const void* __restrict__ qb1,  const void* __restrict__ outb,
    const int* __restrict__ flags,
    unsigned short* __restrict__ Wl0, unsigned short* __restrict__ Wl1,
    unsigned short* __restrict__ Wl2,
    unsigned short* __restrict__ kW0T, unsigned short* __restrict__ kW1T,
    unsigned short* __restrict__ vW0T, unsigned short* __restrict__ vW1T,
    unsigned short* __restrict__ qW0T, unsigned short* __restrict__ qW1T,
    float* __restrict__ bsum,
    unsigned short* __restrict__ outWc, unsigned short* __restrict__ inithc,
    unsigned short* __restrict__ initcc, unsigned short* __restrict__ qb0c,
    unsigned short* __restrict__ qb1c,  unsigned short* __restrict__ outbc)
{
  const int f32 = flags[0];
  int idx = blockIdx.x*256 + threadIdx.x;
  if (idx < 524288){ int r=idx&131071, k=r>>8, gi=r&255;
    int g = ((gi>>6)<<8) + ((idx>>17)<<6) + (gi&63);
    Wl0[idx] = f2b((k<256)? gload(Wih0,(long)g*512+k,f32) : gload(Whh0,(long)g*256+(k-256),f32)); return; }
  idx -= 524288;
  if (idx < 524288){ int r=idx&131071, k=r>>8, gi=r&255;
    int g = ((gi>>6)<<8) + ((idx>>17)<<6) + (gi&63);
    Wl1[idx] = f2b((k<256)? gload(Wih1,(long)g*256+k,f32) : gload(Whh1,(long)g*256+(k-256),f32)); return; }
  idx -= 524288;
  if (idx < 524288){ int r=idx&131071, k=r>>8, gi=r&255;
    int g = ((gi>>6)<<8) + ((idx>>17)<<6) + (gi&63);
    Wl2[idx] = f2b((k<256)? gload(Wih2,(long)g*256+k,f32) : gload(Whh2,(long)g*256+(k-256),f32)); return; }
  idx -= 524288;
  if (idx < 262144){ int k=idx>>9, j=idx&511; kW0T[idx]=f2b(gload(kW0,(long)j*512+k,f32)); return; }
  idx -= 262144;
  if (idx < 32768){ int k=idx>>6, j=idx&63; kW1T[idx]=f2b(gload(kW1,(long)j*512+k,f32)); return; }
  idx -= 32768;
  if (idx < 131072){ int k=idx>>8, j=idx&255; vW0T[idx]=f2b(gload(vW0,(long)j*512+k,f32)); return; }
  idx -= 131072;
  if (idx < 65536){ int k=idx>>8, j=idx&255; vW1T[idx]=f2b(gload(vW1,(long)j*256+k,f32)); return; }
  idx -= 65536;
  if (idx < 65536){ int k=idx>>8, j=idx&255; qW0T[idx]=f2b(gload(qW0,(long)j*256+k,f32)); return; }
  idx -= 65536;
  if (idx < 16384){ int k=idx>>6, j=idx&63; qW1T[idx]=f2b(gload(qW1,(long)j*256+k,f32)); return; }
  idx -= 16384;
  if (idx < 3072){ int l=idx>>10, r=idx&1023, pp=r>>8, gi=r&255;
    int g = ((gi>>6)<<8) + (pp<<6) + (gi&63);
    const void* bi = (l==0)?bih0:((l==1)?bih1:bih2);
    const void* bh = (l==0)?bhh0:((l==1)?bhh1:bhh2);
    bsum[idx] = gload(bi,g,f32)+gload(bh,g,f32); return; }
  idx -= 3072;
  if (idx < 17408){ outWc[idx]=f2b(gload(outW,idx,f32)); return; }
  idx -= 17408;
  if (idx < 768){ inithc[idx]=f2b(gload(inith,idx,f32)); return; }
  idx -= 768;
  if (idx < 768){ initcc[idx]=f2b(gload(initc,idx,f32)); return; }
  idx -= 768;
  if (idx < 256){ qb0c[idx]=f2b(gload(qb0,idx,f32)); return; }
  idx -= 256;
  if (idx < 64){ qb1c[idx]=f2b(gload(qb1,idx,f32)); return; }
  idx -= 64;
  if (idx < 34){ outbc[idx]=f2b(gload(outb,idx,f32)); return; }
}

// gep[p∈4][v][gi∈256] = sum_k emb[v][k] * Wih0[g(p,gi)][256+k]
__global__ __launch_bounds__(256) void prep_ge(
    const void* __restrict__ emb,
    const void* __restrict__ Wih0,
    const int* __restrict__ flags,
    float* __restrict__ gep)
{
  __shared__ float ev[256];
  const int f32 = flags[0];
  const int v = blockIdx.x, tid = threadIdx.x;
  ev[tid] = gload(emb,(long)v*256+tid,f32);
  __syncthreads();
  #pragma unroll
  for (int j=0;j<4;j++){
    const int g = tid*4+j;
    float a = 0.f;
    #pragma unroll 4
    for (int k=0;k<256;k++) a += ev[k]*gload(Wih0,(long)g*512+256+k,f32);
    int pp = (g>>6)&3, gi = ((g>>8)<<6)|(g&63);
    gep[((size_t)pp*34+v)*256+gi] = a;
  }
}

// ---------------------------------------------------------------------------
// key MLP: keyT[n][q][l]  (unchanged)
// ---------------------------------------------------------------------------
__global__ __launch_bounds__(256) void key_mlp(
    const void* __restrict__ seqs,
    const unsigned short* __restrict__ kW0T, const void* __restrict__ kb0,
    const unsigned short* __restrict__ kW1T, const void* __restrict__ kb1,
    const int* __restrict__ flags,
    unsigned short* __restrict__ keyT)
{
  __shared__ float Xt[16*512];
  __shared__ unsigned short Hd[16*512];
  const int f32 = flags[0];
  const int tid = threadIdx.x;
  const int R0 = blockIdx.x*16;
  for (int i=tid;i<8192;i+=256) Xt[i] = gload(seqs,(long)R0*512+i,f32);
  __syncthreads();
  {
    const int j0 = 2*tid;
    float acc0[16], acc1[16];
    #pragma unroll
    for (int r=0;r<16;r++){ acc0[r]=0.f; acc1[r]=0.f; }
    for (int k=0;k<512;k++){
      ushort2 w = *reinterpret_cast<const ushort2*>(kW0T + (size_t)k*512 + j0);
      float w0=b2f(w.x), w1=b2f(w.y);
      #pragma unroll
      for (int r=0;r<16;r++){ float x = Xt[r*512+k]; acc0[r]+=x*w0; acc1[r]+=x*w1; }
    }
    float b0v=gload(kb0,j0,f32), b1v=gload(kb0,j0+1,f32);
    #pragma unroll
    for (int r=0;r<16;r++){
      Hd[r*512+j0]   = f2b(eluf(acc0[r]+b0v));
      Hd[r*512+j0+1] = f2b(eluf(acc1[r]+b1v));
    }
  }
  __syncthreads();
  {
    const int j = tid & 63;
    const int rbase = tid >> 6;
    float acc[4] = {0.f,0.f,0.f,0.f};
    for (int k=0;k<512;k++){
      float w = b2f(kW1T[(size_t)k*64 + j]);
      #pragma unroll
      for (int m=0;m<4;m++) acc[m] += b2f(Hd[(rbase+4*m)*512 + k]) * w;
    }
    float bv = gload(kb1,j,f32);
    #pragma unroll
    for (int m=0;m<4;m++){
      int R = R0 + rbase + 4*m;
      int l = R >> 6, n = R & 63;
      keyT[((size_t)(n*64 + j))*1024 + l] = f2b(acc[m]+bv);
    }
  }
}

// ---------------------------------------------------------------------------
// value MLP: value[n][l][h]  (unchanged)
// ---------------------------------------------------------------------------
__global__ __launch_bounds__(256) void value_mlp(
    const void* __restrict__ seqs,
    const unsigned short* __restrict__ vW0T, const void* __restrict__ vb0,
    const unsigned short* __restrict__ vW1T, const void* __restrict__ vb1,
    const int* __restrict__ flags,
    unsigned short* __restrict__ value)
{
  __shared__ float Xt[16*512];
  __shared__ float Hd[16*256];
  const int f32 = flags[0];
  const int tid = threadIdx.x;
  const int R0 = blockIdx.x*16;
  for (int i=tid;i<8192;i+=256) Xt[i] = gload(seqs,(long)R0*512+i,f32);
  __syncthreads();
  {
    const int j0 = 2*(tid & 127);
    const int rh = tid >> 7;
    float acc0[8], acc1[8];
    #pragma unroll
    for (int r=0;r<8;r++){ acc0[r]=0.f; acc1[r]=0.f; }
    for (int k=0;k<512;k++){
      ushort2 w = *reinterpret_cast<const ushort2*>(vW0T + (size_t)k*256 + j0);
      float w0=b2f(w.x), w1=b2f(w.y);
      #pragma unroll
      for (int r=0;r<8;r++){ float x = Xt[(rh*8+r)*512+k]; acc0[r]+=x*w0; acc1[r]+=x*w1; }
    }
    float b0v=gload(vb0,j0,f32), b1v=gload(vb0,j0+1,f32);
    #pragma unroll
    for (int r=0;r<8;r++){
      Hd[(rh*8+r)*256+j0]   = eluf(acc0[r]+b0v);
      Hd[(rh*8+r)*256+j0+1] = eluf(acc1[r]+b1v);
    }
  }
  __syncthreads();
  {
    const int j = tid;
    float acc[16];
    #pragma unroll
    for (int r=0;r<16;r++) acc[r]=0.f;
    for (int k=0;k<256;k++){
      float w = b2f(vW1T[(size_t)k*256 + j]);
      #pragma unroll
      for (int r=0;r<16;r++) acc[r] += Hd[r*256+k]*w;
    }
    float bv = gload(vb1,j,f32);
    #pragma unroll
    for (int r=0;r<16;r++){
      int R = R0 + r; int l = R>>6, n = R&63;
      value[((size_t)n*1024 + l)*256 + j] = f2b(acc[r]+bv);
    }
  }
}

__global__ __launch_bounds__(256) void zero_hbuf(ull* __restrict__ f){
  int i = blockIdx.x*256 + threadIdx.x;
  if (i < 115200) f[i] = 0;   // tag 0 matches no round (tags start at 1)
}

// ---------------------------------------------------------------------------
// Decode: 256 blocks x 512 threads, 1 block/CU. bid = n*4+p (r6 mapping:
// per-XCD weight slices L2-resident, FETCH 0.41 GB measured). Part p owns
// h-cols [64p,64p+64) per layer + l-quarter [256p..) of attention (value
// quarter in LDS). NEW vs r6: software-pipelined recurrence — each LSTM is
// split into pre (Whh*h_prev, no cross-block dep) and post (Wih*fresh input),
// so every mailbox wait is overlapped with independent compute; polls have
// s_sleep backoff (r7 post-mortem: unthrottled spins -> fabric collapse).
// Mailbox per n (ull, tagged): H0[256] H1[256] H2[256] PC[4][256] ST[4][2].
// ---------------------------------------------------------------------------
__global__ __launch_bounds__(512, 1) void speller(
    const unsigned short* __restrict__ keyT,
    const unsigned short* __restrict__ value,
    const unsigned short* __restrict__ Wl0,
    const unsigned short* __restrict__ Wl1,
    const unsigned short* __restrict__ Wl2,
    const unsigned short* __restrict__ qW0T,
    const unsigned short* __restrict__ qW1T,
    const float* __restrict__ bsum_p,
    const float* __restrict__ gep,
    const unsigned short* __restrict__ inithc,
    const unsigned short* __restrict__ initcc,
    const unsigned short* __restrict__ qb0c,
    const unsigned short* __restrict__ qb1c,
    const unsigned short* __restrict__ outWc,
    const unsigned short* __restrict__ outbc,
    const int* __restrict__ labels,
    const int* __restrict__ seq_lens,
    const int* __restrict__ dflags,
    ull* __restrict__ hbw,
    void* __restrict__ out)
{
  extern __shared__ char smem_dyn[];
  unsigned short* vlds = (unsigned short*)smem_dyn;   // [256 l][256 h] quarter, 128 KB

  __shared__ float sacc[4096];
  __shared__ float garr[256];
  __shared__ float h0[256], h1[256], h2[256], ctx[256];
  __shared__ float cloc[3][64];
  __shared__ float hsl[3][64];
  __shared__ float xq[256];
  __shared__ float qv[64];
  __shared__ float sarr[256], earr[256];
  __shared__ float red[128];
  __shared__ float wf[4];
  __shared__ float pcl[256];
  __shared__ float statl[8];
  __shared__ float so[2];

  const int tid = threadIdx.x;
  const int n = blockIdx.x >> 2;     // bid = n*4 + p
  const int p = blockIdx.x & 3;
  const int f32o = dflags[0];
  const int i64 = dflags[1];
  const int slen = i64 ? seq_lens[2*n] : seq_lens[n];

  ull* mb   = hbw + (size_t)n*1800;
  ull* H0w  = mb;            // [256]
  ull* H1w  = mb + 256;      // [256]
  ull* H2w  = mb + 512;      // [256]
  ull* PCw  = mb + 768;      // [4][256]
  ull* STw  = mb + 1792;     // [4][2]

  // preload value quarter into LDS (once)
  {
    const uint4* src = (const uint4*)(value + ((size_t)n*1024 + p*256)*256);
    uint4* dst = (uint4*)vlds;
    for (int i=tid;i<16384;i+=512) dst[i] = src[i];
  }
  if (tid < 256){ h0[tid]=b2f(inithc[tid]); h1[tid]=b2f(inithc[256+tid]); h2[tid]=b2f(inithc[512+tid]); }
  if (tid < 64){
    cloc[0][tid]=b2f(initcc[p*64+tid]);
    cloc[1][tid]=b2f(initcc[256+p*64+tid]);
    cloc[2][tid]=b2f(initcc[512+p*64+tid]);
  }
  __syncthreads();

  const int ks = tid >> 5;          // 16 k-chunks of 16
  const int g8 = tid & 31;          // 8-gate oct: gi = g8*8..+8

  // pre: hh half (k in [256,512)) from h_prev — no cross-block dependency.
  auto lstm_pre = [&](const unsigned short* W, const float* hprev, float* a){
    const unsigned short* wp = W + (size_t)p*131072 + (size_t)(256 + ks*16)*256 + g8*8;
    const float* x = hprev + ks*16;
    #pragma unroll
    for (int k=0;k<16;k++){
      float xv = x[k];
      uint4 w = *reinterpret_cast<const uint4*>(wp + (size_t)k*256);
      a[0]+=xv*lo16(w.x); a[1]+=xv*hi16(w.x);
      a[2]+=xv*lo16(w.y); a[3]+=xv*hi16(w.y);
      a[4]+=xv*lo16(w.z); a[5]+=xv*hi16(w.z);
      a[6]+=xv*lo16(w.w); a[7]+=xv*hi16(w.w);
    }
  };
  // post: ih half (k in [0,256)) from fresh input; reduce; gates; publish.
  auto lstm_post = [&](const unsigned short* W, const float* xin, float* a,
                       const float* bs, const float* ger, int layer,
                       ull* Hw, unsigned tag){
    const unsigned short* wp = W + (size_t)p*131072 + (size_t)(ks*16)*256 + g8*8;
    const float* x = xin + ks*16;
    #pragma unroll
    for (int k=0;k<16;k++){
      float xv = x[k];
      uint4 w = *reinterpret_cast<const uint4*>(wp + (size_t)k*256);
      a[0]+=xv*lo16(w.x); a[1]+=xv*hi16(w.x);
      a[2]+=xv*lo16(w.y); a[3]+=xv*hi16(w.y);
      a[4]+=xv*lo16(w.z); a[5]+=xv*hi16(w.z);
      a[6]+=xv*lo16(w.w); a[7]+=xv*hi16(w.w);
    }
    float* sb = sacc + ks*256 + g8*8;
    sb[0]=a[0]; sb[1]=a[1]; sb[2]=a[2]; sb[3]=a[3];
    sb[4]=a[4]; sb[5]=a[5]; sb[6]=a[6]; sb[7]=a[7];
    __syncthreads();
    if (tid < 256){
      float s = bs[tid] + (ger ? ger[tid] : 0.f);
      #pragma unroll
      for (int u=0;u<16;u++) s += sacc[u*256+tid];
      garr[tid] = s;
    }
    __syncthreads();
    if (tid < 64){
      float gi=garr[tid], gf=garr[64+tid], gg=garr[128+tid], go=garr[192+tid];
      float cc = sigf(gf)*cloc[layer][tid] + sigf(gi)*tanhf(gg);
      float hh = sigf(go)*tanhf(cc);
      cloc[layer][tid]=cc;
      hsl[layer][tid]=hh;
      ast64(Hw + p*64 + tid, pk(hh, tag));
    }
    // no trailing barrier: gather/pre sequence opens with one
  };

  // gather full h: own slice from LDS, 3 remote slices by backoff-poll.
  auto gather_h = [&](const ull* Hw, int layer, unsigned tag, float* hdst){
    __syncthreads();   // covers hsl write by wave 0
    if (tid < 256){
      int sp = tid >> 6; float v;
      if (sp == p) v = hsl[layer][tid & 63];
      else v = pollw(Hw + tid, tag);
      hdst[tid] = v;
    }
    __syncthreads();
  };

  // attention compute: replicated q-MLP from full h2, own l-quarter scores,
  // softmax partials + partial ctx -> mailbox. No polls here.
  auto attn_comp = [&](unsigned tag){
    { // xq replicated: col j, two k-halves of 128
      const int j = tid & 255, kh = tid >> 8;
      const unsigned short* qp = qW0T + (size_t)(kh*128)*256 + j;
      float a = 0.f;
      #pragma unroll 8
      for (int k=0;k<128;k++) a += h2[kh*128+k]*b2f(qp[(size_t)k*256]);
      sacc[kh*256 + j] = a;
    }
    __syncthreads();
    if (tid < 256) xq[tid] = eluf(sacc[tid]+sacc[256+tid] + b2f(qb0c[tid]));
    __syncthreads();
    { // qv: 64 cols x 8 k-strips of 32
      const int qc = tid & 63, k8 = tid >> 6;
      float a = 0.f;
      const unsigned short* qp = qW1T + qc;
      #pragma unroll 8
      for (int k=0;k<32;k++){ int kk = k8*32+k; a += xq[kk]*b2f(qp[(size_t)kk*64]); }
      sacc[k8*64+qc] = a;
    }
    __syncthreads();
    if (tid < 64){
      float s=0.f;
      #pragma unroll
      for (int u=0;u<8;u++) s += sacc[u*64+tid];
      qv[tid] = s + b2f(qb1c[tid]);
    }
    __syncthreads();
    { // scores own l-quarter: l-pairs x 4 q-chunks of 16
      const int lp = tid & 127, qh = tid >> 7;
      float a0=0.f,a1=0.f;
      const unsigned short* kp = keyT + (size_t)n*65536 + (size_t)qh*16*1024 + p*256 + 2*lp;
      #pragma unroll 8
      for (int q=0;q<16;q++){
        ushort2 w = *reinterpret_cast<const ushort2*>(kp + (size_t)q*1024);
        float qq = qv[qh*16+q];
        a0 += qq*b2f(w.x); a1 += qq*b2f(w.y);
      }
      sacc[qh*256+2*lp]=a0; sacc[qh*256+2*lp+1]=a1;
    }
    __syncthreads();
    if (tid < 256){
      float s = sacc[tid]+sacc[256+tid]+sacc[512+tid]+sacc[768+tid];
      sarr[tid] = (p*256+tid < slen) ? s : -1e30f;
    }
    __syncthreads();
    if (tid < 128) red[tid] = fmaxf(sarr[tid], sarr[tid+128]);
    __syncthreads();
    for (int s=64;s>0;s>>=1){ if (tid<s) red[tid]=fmaxf(red[tid],red[tid+s]); __syncthreads(); }
    const float pmax = red[0];
    __syncthreads();
    if (tid < 256) earr[tid] = (p*256+tid < slen) ? __expf(sarr[tid]-pmax) : 0.f;
    __syncthreads();
    if (tid < 128) red[tid] = earr[tid]+earr[tid+128];
    __syncthreads();
    for (int s=64;s>0;s>>=1){ if (tid<s) red[tid]+=red[tid+s]; __syncthreads(); }
    const float psum = red[0];
    { // partial ctx from LDS value: h-pairs x 4 l-chunks of 64
      const int hp = tid & 127, lq = tid >> 7;
      float a0=0.f,a1=0.f;
      const unsigned short* vp = vlds + (size_t)(lq*64)*256 + 2*hp;
      #pragma unroll 8
      for (int l=0;l<64;l++){
        ushort2 w = *reinterpret_cast<const ushort2*>(vp + (size_t)l*256);
        float e = earr[lq*64+l];
        a0 += e*b2f(w.x); a1 += e*b2f(w.y);
      }
      sacc[lq*256+2*hp]=a0; sacc[lq*256+2*hp+1]=a1;
    }
    __syncthreads();
    if (tid < 256){
      float v = sacc[tid]+sacc[256+tid]+sacc[512+tid]+sacc[768+tid];
      pcl[tid] = v;
      ast64(PCw + p*256 + tid, pk(v, tag));
    }
    if (tid == 0){
      so[0]=pmax; so[1]=psum;
      ast64(STw + p*2, pk(pmax, tag)); ast64(STw + p*2 + 1, pk(psum, tag));
    }
  };

  // attention finalize: gather stats + pctx (backoff polls), exact assembly.
  auto attn_fin = [&](unsigned tag){
    __syncthreads();   // covers so/pcl writes in comp
    if (tid < 8){
      int q = tid >> 1, ix = tid & 1; float v;
      if (q == p) v = so[ix];
      else v = pollw(STw + q*2 + ix, tag);
      statl[tid] = v;
    }
    __syncthreads();
    if (tid == 0){
      float m0=statl[0], s0=statl[1], m1=statl[2], s1=statl[3];
      float m2=statl[4], s2=statl[5], m3=statl[6], s3=statl[7];
      float M = fmaxf(fmaxf(m0,m1),fmaxf(m2,m3));
      float w0=__expf(m0-M), w1=__expf(m1-M), w2=__expf(m2-M), w3=__expf(m3-M);
      float inv = 1.f/(s0*w0+s1*w1+s2*w2+s3*w3);
      wf[0]=w0*inv; wf[1]=w1*inv; wf[2]=w2*inv; wf[3]=w3*inv;
    }
    __syncthreads();
    if (tid < 256){
      float acc = pcl[tid]*wf[p];
      #pragma unroll
      for (int q=0;q<4;q++){
        if (q == p) continue;
        acc += pollw(PCw + q*256 + tid, tag)*wf[q];
      }
      ctx[tid] = acc;
    }
    __syncthreads();
  };

  // out projection for step t (reads current ctx/h2 contents).
  auto outproj = [&](int t){
    const int ri = tid >> 6, kk = tid & 63;
    const int r = 4*ri + p;
    float acc = 0.f;
    const unsigned short* wr = outWc + (size_t)r*512 + kk;
    #pragma unroll
    for (int s=0;s<4;s++) acc += ctx[s*64+kk]*b2f(wr[s*64]);
    #pragma unroll
    for (int s=0;s<4;s++) acc += h2[s*64+kk]*b2f(wr[256+s*64]);
    #pragma unroll
    for (int off=32; off>0; off>>=1) acc += __shfl_down(acc, off);
    if (kk==0){
      float v = acc + b2f(outbc[r]);
      size_t oi = ((size_t)(t*64+n))*34 + r;
      if (f32o) ((float*)out)[oi]=v; else ((unsigned short*)out)[oi]=f2b(v);
    }
    if (p < 2 && tid < 64){
      const int r2 = 32+p;
      float a2=0.f;
      const unsigned short* wr2 = outWc + (size_t)r2*512 + tid;
      #pragma unroll
      for (int s=0;s<4;s++) a2 += ctx[s*64+tid]*b2f(wr2[s*64]);
      #pragma unroll
      for (int s=0;s<4;s++) a2 += h2[s*64+tid]*b2f(wr2[256+s*64]);
      #pragma unroll
      for (int off=32; off>0; off>>=1) a2 += __shfl_down(a2, off);
      if (tid==0){
        float v = a2 + b2f(outbc[r2]);
        size_t oi = ((size_t)(t*64+n))*34 + r2;
        if (f32o) ((float*)out)[oi]=v; else ((unsigned short*)out)[oi]=f2b(v);
      }
    }
  };

  // prologue: prev_ctx from inith2 (h2 local everywhere, no gather needed)
  attn_comp(1);   // PC tag 1

  for (int t=0;t<256;t++){
    const unsigned ht = (unsigned)t + 1;   // H tags this iter
    const int lab = i64 ? labels[2*(t*64+n)] : labels[t*64+n];
    float a[8];
    // --- L0: pre (hh from h0_prev) overlaps the ctx finalize
    #pragma unroll
    for (int i=0;i<8;i++) a[i]=0.f;
    lstm_pre(Wl0, h0, a);
    attn_fin(ht);   // ctx_in(t): PC tag t+1 (prologue published 1)
    lstm_post(Wl0, ctx, a, bsum_p + p*256, gep + ((size_t)p*34+lab)*256, 0, H0w, ht);
    // --- L1: pre (hh from h1_prev) overlaps gather of H0
    #pragma unroll
    for (int i=0;i<8;i++) a[i]=0.f;
    lstm_pre(Wl1, h1, a);
    gather_h(H0w, 0, ht, h0);
    lstm_post(Wl1, h0, a, bsum_p + 1024 + p*256, nullptr, 1, H1w, ht);
    // --- L2: pre (hh from h2_prev) overlaps gather of H1
    #pragma unroll
    for (int i=0;i<8;i++) a[i]=0.f;
    lstm_pre(Wl2, h2, a);
    gather_h(H1w, 1, ht, h1);
    lstm_post(Wl2, h1, a, bsum_p + 2048 + p*256, nullptr, 2, H2w, ht);
    // --- out(t-1) overlaps gather of H2: ctx holds ctx(t-1), h2 holds h2(t-1)
    if (t > 0){ __syncthreads(); outproj(t-1); }
    gather_h(H2w, 2, ht, h2);
    // --- attention for step t (publishes PC tag t+2; consumed next iter)
    attn_comp((unsigned)t + 2);
  }
  // epilogue: finalize ctx(255) (PC tag 257) and emit out(255)
  attn_fin(257);
  outproj(255);
}

extern "C" void kernel_launch(void* const* d_in, const int* in_sizes, int n_in,
                              void* d_out, int out_size, void* d_ws, size_t ws_size,
                              hipStream_t stream) {
  const void* seqs  = d_in[0];
  const int* seq_lens = (const int*)d_in[1];
  const int* labels   = (const int*)d_in[2];
  const void* emb   = d_in[3];
  const void* inith = d_in[4];
  const void* initc = d_in[5];
  const void* Wih0 = d_in[6];  const void* Whh0 = d_in[7];
  const void* bih0 = d_in[8];  const void* bhh0 = d_in[9];
  const void* Wih1 = d_in[10]; const void* Whh1 = d_in[11];
  const void* bih1 = d_in[12]; const void* bhh1 = d_in[13];
  const void* Wih2 = d_in[14]; const void* Whh2 = d_in[15];
  const void* bih2 = d_in[16]; const void* bhh2 = d_in[17];
  const void* qW0 = d_in[18];  const void* qb0 = d_in[19];
  const void* qW1 = d_in[20];  const void* qb1 = d_in[21];
  const void* kW0 = d_in[22];  const void* kb0 = d_in[23];
  const void* kW1 = d_in[24];  const void* kb1 = d_in[25];
  const void* vW0 = d_in[26];  const void* vb0 = d_in[27];
  const void* vW1 = d_in[28];  const void* vb1 = d_in[29];
  const void* outW = d_in[30]; const void* outb = d_in[31];

  char* ws = (char*)d_ws;
  unsigned short* keyT  = (unsigned short*)(ws);             //  8,388,608 B  [64][64][1024]
  unsigned short* value = (unsigned short*)(ws + 8388608);   // 33,554,432 B  [64][1024][256]
  unsigned short* Wl0   = (unsigned short*)(ws + 41943040);  //  1,048,576 B  [4][512][256]
  unsigned short* Wl1   = (unsigned short*)(ws + 42991616);
  unsigned short* Wl2   = (unsigned short*)(ws + 44040192);
  unsigned short* kW0T  = (unsigned short*)(ws + 45088768);  //    524,288 B (prep-only)
  unsigned short* kW1T  = (unsigned short*)(ws + 45613056);  //     65,536 B (prep-only)
  unsigned short* vW0T  = (unsigned short*)(ws + 45678592);  //    262,144 B (prep-only)
  unsigned short* vW1T  = (unsigned short*)(ws + 45940736);  //    131,072 B (prep-only)
  unsigned short* qW0T  = (unsigned short*)(ws + 46071808);  //    131,072 B
  unsigned short* qW1T  = (unsigned short*)(ws + 46202880);  //     32,768 B
  float*          bsum  = (float*)(ws + 46235648);           //     12,288 B  [3][4][256]
  float*          gep   = (float*)(ws + 46247936);           //    139,264 B  [4][34][256]
  unsigned short* outWc = (unsigned short*)(ws + 46387200);  //     34,816 B
  unsigned short* inithc= (unsigned short*)(ws + 46422016);  //      1,536 B
  unsigned short* initcc= (unsigned short*)(ws + 46423552);  //      1,536 B
  unsigned short* qb0c  = (unsigned short*)(ws + 46425088);  //        512 B
  unsigned short* qb1c  = (unsigned short*)(ws + 46425600);  //        128 B
  unsigned short* outbc = (unsigned short*)(ws + 46425728);  //        128 B
  int*            dflags= (int*)(ws + 46425856);             //         16 B
  // tagged mailbox overlaps kW0T..vW1T (prep-only, consumed before speller):
  ull* hbw = (ull*)(ws + 45088768);                          //    921,600 B  [64][1800]

  sniff<<<dim3(1), dim3(64), 0, stream>>>(seqs, seq_lens, dflags);
  prep_transpose<<<dim3(8472), dim3(256), 0, stream>>>(
      Wih0,Whh0,Wih1,Whh1,Wih2,Whh2, kW0,kW1,vW0,vW1,qW0,qW1,
      bih0,bhh0,bih1,bhh1,bih2,bhh2,
      outW,inith,initc,qb0,qb1,outb, dflags,
      Wl0,Wl1,Wl2,kW0T,kW1T,vW0T,vW1T,qW0T,qW1T,bsum,
      outWc,inithc,initcc,qb0c,qb1c,outbc);
  prep_ge<<<dim3(34), dim3(256), 0, stream>>>(emb, Wih0, dflags, gep);
  key_mlp<<<dim3(4096), dim3(256), 0, stream>>>(seqs, kW0T, kb0, kW1T, kb1, dflags, keyT);
  value_mlp<<<dim3(4096), dim3(256), 0, stream>>>(seqs, vW0T, vb0, vW1T, vb1, dflags, value);
  zero_hbuf<<<dim3(450), dim3(256), 0, stream>>>(hbw);
  hipFuncSetAttribute((const void*)speller, hipFuncAttributeMaxDynamicSharedMemorySize, 131072);
  speller<<<dim3(256), dim3(512), 131072, stream>>>(
      keyT, value, Wl0, Wl1, Wl2, qW0T, qW1T, bsum, gep,
      inithc, initcc, qb0c, qb1c, outWc, outbc, labels, seq_lens, dflags,
      hbw, d_out);
}